// Round 1
// baseline (71.002 us; speedup 1.0000x reference)
//
#include <hip/hip_runtime.h>

#define Bn 32
#define Nn 256
#define Hn 128
#define En 16
#define WWC (Hn + En)   // 144, W_w row stride

typedef float v4 __attribute__((ext_vector_type(4)));

// ---------------- K0: gate[i][j] = (sum_b adj[b,i,j]) > 0 ----------------
__global__ __launch_bounds__(256) void k_gate(const int* __restrict__ adj, float* __restrict__ gate) {
    int i = blockIdx.x, j = threadIdx.x;
    int s = 0;
    #pragma unroll
    for (int b = 0; b < Bn; ++b) s += adj[(b * Nn + i) * Nn + j];
    gate[i * Nn + j] = (s > 0) ? 1.0f : 0.0f;
}

// ------ K0b: per column j: count[j], zero-count, zero index list (deterministic, ballot compaction) ------
__global__ __launch_bounds__(256) void k_count(const float* __restrict__ gate, float* __restrict__ count,
                                               int* __restrict__ zcnt, int* __restrict__ zlist) {
    int j = blockIdx.x, t = threadIdx.x;
    bool z = (gate[t * Nn + j] == 0.0f);
    unsigned long long m = __ballot(z);
    int lane = t & 63, w = t >> 6;
    __shared__ int wc[4];
    if (lane == 0) wc[w] = (int)__popcll(m);
    __syncthreads();
    int off = 0;
    for (int q = 0; q < w; ++q) off += wc[q];
    if (z) zlist[j * Nn + off + (int)__popcll(m & ((1ull << lane) - 1ull))] = t;
    if (t == 0) {
        int tot = wc[0] + wc[1] + wc[2] + wc[3];
        zcnt[j] = tot;
        count[j] = (float)(Nn - tot);
    }
}

// ---------------- KP: P[b][h] = sum_i h[b,i,h] ----------------
__global__ __launch_bounds__(128) void k_psum(const float* __restrict__ h, float* __restrict__ P) {
    int b = blockIdx.x, hh = threadIdx.x;
    float s = 0.f;
    #pragma unroll 8
    for (int i = 0; i < Nn; ++i) s += h[(b * Nn + i) * Hn + hh];
    P[b * Hn + hh] = s;
}

// ---------------- K2a: U_T[m][o] = U_w[o][m] ----------------
__global__ __launch_bounds__(128) void k_ut(const float* __restrict__ U_w, float* __restrict__ U_T) {
    int m = blockIdx.x, o = threadIdx.x;
    U_T[m * Hn + o] = U_w[o * Hn + m];
}

// ------ K2b: A_T[h][o] = sum_m U_w[o,m]*W_w[m,h];  Bm_T[e][o]; cvec[o] ------
__global__ __launch_bounds__(128) void k_fold(const float* __restrict__ U_T, const float* __restrict__ W_w,
                                              const float* __restrict__ W_b, float* __restrict__ A_T,
                                              float* __restrict__ Bm_T, float* __restrict__ cvec) {
    int bid = blockIdx.x, o = threadIdx.x;
    float s = 0.f;
    if (bid < Hn) {
        #pragma unroll 8
        for (int m = 0; m < Hn; ++m) s += U_T[m * Hn + o] * W_w[m * WWC + bid];
        A_T[bid * Hn + o] = s;
    } else if (bid < Hn + En) {
        int e = bid - Hn;
        #pragma unroll 8
        for (int m = 0; m < Hn; ++m) s += U_T[m * Hn + o] * W_w[m * WWC + Hn + e];
        Bm_T[e * Hn + o] = s;
    } else {
        #pragma unroll 8
        for (int m = 0; m < Hn; ++m) s += U_T[m * Hn + o] * W_b[m];
        cvec[o] = s;
    }
}

// ---------------- KB: baseA[b][o] = sum_h P[b,h]*A_T[h][o] ----------------
__global__ __launch_bounds__(128) void k_base(const float* __restrict__ P, const float* __restrict__ A_T,
                                              float* __restrict__ baseA) {
    int b = blockIdx.x, o = threadIdx.x;
    float s = 0.f;
    #pragma unroll 8
    for (int hh = 0; hh < Hn; ++hh) s += P[b * Hn + hh] * A_T[hh * Hn + o];
    baseA[b * Hn + o] = s;
}

// ---------------- K1: e_sum[b,j,e] = sum_i gate[i,j]*edge[b,i,j,e] ----------------
// grid (Nn/8 jtiles, Bn), 256 threads. Streams the 128MB edge_attr, fully coalesced.
__global__ __launch_bounds__(256) void k_esum(const float* __restrict__ edge, const float* __restrict__ gate,
                                              float* __restrict__ e_sum) {
    int j0 = blockIdx.x * 8, b = blockIdx.y;
    int t = threadIdx.x;
    __shared__ float sg[Nn][8];
    __shared__ v4 sr[8][32];
    // stage gate tile [256][8]
    #pragma unroll
    for (int q = 0; q < 2; ++q) {
        int f = t + 256 * q;
        int i = f >> 1, c = f & 1;
        *reinterpret_cast<v4*>(&sg[i][c * 4]) =
            *reinterpret_cast<const v4*>(&gate[i * Nn + j0 + c * 4]);
    }
    __syncthreads();
    int ig = t >> 5, s = t & 31, jj = s >> 2, e4 = (s & 3) * 4;
    v4 acc = {0.f, 0.f, 0.f, 0.f};
    const float* base = edge + ((size_t)b * Nn * Nn + (size_t)(j0 + jj)) * En + e4;
    #pragma unroll 4
    for (int i = ig; i < Nn; i += 8) {
        float g = sg[i][jj];
        v4 v = *reinterpret_cast<const v4*>(base + (size_t)i * Nn * En);
        acc += g * v;
    }
    sr[ig][s] = acc;
    __syncthreads();
    if (t < 32) {
        v4 tot = sr[0][t];
        #pragma unroll
        for (int q = 1; q < 8; ++q) tot += sr[q][t];
        int jj2 = t >> 2, e42 = (t & 3) * 4;
        *reinterpret_cast<v4*>(&e_sum[((size_t)b * Nn + j0 + jj2) * En + e42]) = tot;
    }
}

// ---------------- K3: fused final ----------------
// out[b,j,o] = sum_m h[b,j,m]*U_T[m][o] + U_b[o]
//            + mask(j)*( baseA[b,o] - corr + sum_e e_sum[b,j,e]*Bm_T[e][o] + count[j]*cvec[o] )
// grid (Nn/32 jtiles, Bn), 512 threads; thread tile: 2 j x 4 o.
__global__ __launch_bounds__(512) void k_final(
    const float* __restrict__ h, const float* __restrict__ U_T, const float* __restrict__ U_b,
    const float* __restrict__ baseA, const float* __restrict__ cvec, const float* __restrict__ Bm_T,
    const float* __restrict__ count, const int* __restrict__ zcnt, const int* __restrict__ zlist,
    const float* __restrict__ A_T, const float* __restrict__ e_sum, const int* __restrict__ num_nodes,
    float* __restrict__ out) {
    int j0 = blockIdx.x * 32, b = blockIdx.y;
    int t = threadIdx.x;
    __shared__ float shj[Hn][33];     // h tile transposed [m][j], padded
    __shared__ float ses[32][En];
    __shared__ float sbm[En][Hn];
    __shared__ float sb[Hn], sc[Hn], sub[Hn], scnt[32];

    // stage h tile (transpose): 4096 floats
    #pragma unroll
    for (int q = 0; q < 2; ++q) {
        int f = t + 512 * q;
        int j = f >> 5, c = f & 31;
        v4 v = *reinterpret_cast<const v4*>(&h[((size_t)b * Nn + j0 + j) * Hn + c * 4]);
        shj[c * 4 + 0][j] = v[0];
        shj[c * 4 + 1][j] = v[1];
        shj[c * 4 + 2][j] = v[2];
        shj[c * 4 + 3][j] = v[3];
    }
    if (t < 128) {
        int j = t >> 2, c = t & 3;
        *reinterpret_cast<v4*>(&ses[j][c * 4]) =
            *reinterpret_cast<const v4*>(&e_sum[((size_t)b * Nn + j0 + j) * En + c * 4]);
    }
    {
        int e = t >> 5, c = t & 31;
        *reinterpret_cast<v4*>(&sbm[e][c * 4]) = *reinterpret_cast<const v4*>(&Bm_T[e * Hn + c * 4]);
    }
    if (t < 32) {
        *reinterpret_cast<v4*>(&sb[t * 4])  = *reinterpret_cast<const v4*>(&baseA[b * Hn + t * 4]);
        *reinterpret_cast<v4*>(&sc[t * 4])  = *reinterpret_cast<const v4*>(&cvec[t * 4]);
        *reinterpret_cast<v4*>(&sub[t * 4]) = *reinterpret_cast<const v4*>(&U_b[t * 4]);
        scnt[t] = count[j0 + t];
    }
    __syncthreads();

    int jq = t >> 5, og = t & 31;
    int j2 = jq * 2, o4 = og * 4;
    v4 acc0 = {0.f, 0.f, 0.f, 0.f}, acc1 = {0.f, 0.f, 0.f, 0.f};
    #pragma unroll 8
    for (int m = 0; m < Hn; ++m) {
        v4 u = *reinterpret_cast<const v4*>(&U_T[m * Hn + o4]);
        float h0 = shj[m][j2], h1 = shj[m][j2 + 1];
        acc0 += h0 * u;
        acc1 += h1 * u;
    }
    int nn = num_nodes[b];
    #pragma unroll
    for (int jj = 0; jj < 2; ++jj) {
        int j = j0 + j2 + jj;
        v4 fa = jj ? acc1 : acc0;
        v4 msg = *reinterpret_cast<v4*>(&sb[o4]);
        #pragma unroll
        for (int e = 0; e < En; ++e)
            msg += ses[j2 + jj][e] * *reinterpret_cast<v4*>(&sbm[e][o4]);
        msg += scnt[j2 + jj] * *reinterpret_cast<v4*>(&sc[o4]);
        int zc = zcnt[j];
        if (zc > 0) {  // sparse exact correction (normally never taken)
            v4 corr = {0.f, 0.f, 0.f, 0.f};
            for (int z = 0; z < zc; ++z) {
                int i = zlist[j * Nn + z];
                for (int hh = 0; hh < Hn; ++hh)
                    corr += h[((size_t)b * Nn + i) * Hn + hh] *
                            *reinterpret_cast<const v4*>(&A_T[hh * Hn + o4]);
            }
            msg -= corr;
        }
        float maskv = (j < nn) ? 1.0f : 0.0f;
        v4 res = fa + *reinterpret_cast<v4*>(&sub[o4]) + maskv * msg;
        *reinterpret_cast<v4*>(&out[((size_t)b * Nn + j) * Hn + o4]) = res;
    }
}

extern "C" void kernel_launch(void* const* d_in, const int* in_sizes, int n_in,
                              void* d_out, int out_size, void* d_ws, size_t ws_size,
                              hipStream_t stream) {
    const float* h    = (const float*)d_in[0];
    const float* edge = (const float*)d_in[1];
    const int*   adj  = (const int*)d_in[2];
    const int*   nn   = (const int*)d_in[3];
    const float* W_w  = (const float*)d_in[4];
    const float* W_b  = (const float*)d_in[5];
    const float* U_w  = (const float*)d_in[6];
    const float* U_b  = (const float*)d_in[7];
    float* out = (float*)d_out;

    float* ws    = (float*)d_ws;
    float* gate  = ws;                 // 65536
    float* count = ws + 65536;         // 256
    int*   zcnt  = (int*)(ws + 65792); // 256
    int*   zlist = (int*)(ws + 66048); // 65536
    float* P     = ws + 131584;        // 4096
    float* U_T   = ws + 135680;        // 16384
    float* A_T   = ws + 152064;        // 16384
    float* Bm_T  = ws + 168448;        // 2048
    float* cvec  = ws + 170496;        // 128
    float* baseA = ws + 170624;        // 4096
    float* e_sum = ws + 174720;        // 131072

    hipLaunchKernelGGL(k_gate,  dim3(Nn),            dim3(256), 0, stream, adj, gate);
    hipLaunchKernelGGL(k_count, dim3(Nn),            dim3(256), 0, stream, gate, count, zcnt, zlist);
    hipLaunchKernelGGL(k_ut,    dim3(Hn),            dim3(128), 0, stream, U_w, U_T);
    hipLaunchKernelGGL(k_fold,  dim3(Hn + En + 1),   dim3(128), 0, stream, U_T, W_w, W_b, A_T, Bm_T, cvec);
    hipLaunchKernelGGL(k_psum,  dim3(Bn),            dim3(128), 0, stream, h, P);
    hipLaunchKernelGGL(k_base,  dim3(Bn),            dim3(128), 0, stream, P, A_T, baseA);
    hipLaunchKernelGGL(k_esum,  dim3(Nn / 8, Bn),    dim3(256), 0, stream, edge, gate, e_sum);
    hipLaunchKernelGGL(k_final, dim3(Nn / 32, Bn),   dim3(512), 0, stream,
                       h, U_T, U_b, baseA, cvec, Bm_T, count, zcnt, zlist, A_T, e_sum, nn, out);
}